// Round 11
// baseline (158.030 us; speedup 1.0000x reference)
//
#include <hip/hip_runtime.h>
#include <hip/hip_bf16.h>
#include <hip/hip_cooperative_groups.h>

namespace cg = cooperative_groups;

#define LOG2E 1.44269504088896340736f
#define C2G   0.39894228040143267794f   // 1/sqrt(2*pi)
#define K2M  -0.79788456080286535588f   // -2*C2G

typedef __attribute__((ext_vector_type(4))) float f32x4;
typedef __attribute__((ext_vector_type(8))) short s16x8;
typedef __attribute__((ext_vector_type(4))) short s16x4;

// ---------------- workspace layout (float offsets) ----------------
static constexpr size_t QF_OFF   = 0;        // [4h][64nt][2s][64l][8j] bf16
static constexpr size_t KF_OFF   = 131072;   // same shape (m-tiles)
static constexpr size_t VF_OFF   = 262144;   // [32ks][8tc][64l][8j] bf16
static constexpr size_t PACC_OFF = 327680;   // [8 chunk][1024 n][128 c] fp32
static constexpr size_t PMAX_OFF = 1376256;  // [8][4][1024]
static constexpr size_t PSUM_OFF = 1409024;  // [8][4][1024]
static constexpr size_t WOB_OFF  = 1441792;  // Wo bf16 linear [c*128+k], 16384 ush
// total = 1,449,984 floats = 5.53 MB

__device__ __forceinline__ short f2bfs(float f){
    __hip_bfloat16 h = __float2bfloat16(f);
    return __builtin_bit_cast(short, h);
}
__device__ __forceinline__ float bf2f(unsigned short u){
    return __builtin_bit_cast(float, ((unsigned)u) << 16);
}
__device__ __forceinline__ float wave_sum64(float v){
    #pragma unroll
    for (int m = 32; m >= 1; m >>= 1) v += __shfl_xor(v, m, 64);
    return v;
}

// ---------------- single cooperative kernel: 3 phases, 2 grid syncs ------
// grid 512 x 256 (2 blocks/CU co-resident; LDS 41KB/block).
// Phase 1: b = bx*8+sub. sub<6: projection c-half (mat=sub>>1, ch=sub&1);
//          sub==6: pos terms; sub==7 (bx<8): Wo->bf16 conversion.
// Phase 2: attention, bx=b>>3, by=b&7 (R9 k_attn verbatim).
// Phase 3: b<256: combine + split-k fp32 Wo GEMM + residual + LN (R9 k_final).
// Fragment k-bijections (HW-validated R5-R9):
//   scores g(l,j) = (l>>4)*8 + j ; PV f(l,j) = (l>>4)*4 + (j&3) + 16*(j>>2)
__global__ __launch_bounds__(256, 2) void k_fused(
    const float* __restrict__ x, const float* __restrict__ xyz,
    const float* __restrict__ Wq, const float* __restrict__ Wk,
    const float* __restrict__ Wv, const float* __restrict__ Wp1,
    const float* __restrict__ bp1, const float* __restrict__ Wp2,
    const float* __restrict__ bp2, const float* __restrict__ Wo,
    const float* __restrict__ bo, const float* __restrict__ gamma,
    const float* __restrict__ beta, float* __restrict__ ws,
    float* __restrict__ out)
{
    __shared__ __align__(16) char smraw[41024];
    const int t = threadIdx.x, l = t & 63, w = t >> 6;
    const int g = l >> 4, col = l & 15;
    const int b = blockIdx.x;

    // ================= PHASE 1 =================
    {
        const int bx = b >> 3, sub = b & 7;
        const int n0 = bx * 16;
        if (sub < 6){
            // projection c-half block: output c in [ch*64, ch*64+64), n-tile bx
            ushort* wbf   = (ushort*)smraw;            // [64][130] bf16 W-half
            float*  xlds  = (float*)(smraw + 16640);   // [128k][16n]
            float*  stage = (float*)(smraw + 24832);   // [64c][17]
            const int mat = sub >> 1, ch = sub & 1;
            const float* Wh = ((mat==0)?Wq:(mat==1?Wk:Wv)) + (size_t)ch*64*128;
            for (int i = t; i < 2048; i += 256){
                const float4 w4 = ((const float4*)Wh)[i];
                const int r = (i*4) >> 7, k = (i*4) & 127;
                wbf[r*130+k+0] = (ushort)f2bfs(w4.x);
                wbf[r*130+k+1] = (ushort)f2bfs(w4.y);
                wbf[r*130+k+2] = (ushort)f2bfs(w4.z);
                wbf[r*130+k+3] = (ushort)f2bfs(w4.w);
            }
            for (int i = t; i < 2048; i += 256)
                xlds[i] = x[(size_t)(i>>4)*1024 + n0 + (i&15)];
            __syncthreads();

            const int cl = t & 63, ng = t >> 6;
            float acc[4] = {0,0,0,0};
            #pragma unroll 4
            for (int k = 0; k < 128; k++){
                const float wv = bf2f(wbf[cl*130 + k]);
                const float4 a = *(const float4*)&xlds[k*16 + ng*4];
                acc[0] = fmaf(wv, a.x, acc[0]);
                acc[1] = fmaf(wv, a.y, acc[1]);
                acc[2] = fmaf(wv, a.z, acc[2]);
                acc[3] = fmaf(wv, a.w, acc[3]);
            }
            #pragma unroll
            for (int i = 0; i < 4; i++)
                stage[cl*17 + ng*4 + i] = acc[i];
            __syncthreads();

            if (mat != 2){
                if (w < 2){   // this c-half covers heads {2ch, 2ch+1}
                    const int hg = ch*2 + w;
                    const float qs = (mat==0) ? 0.17677669529663689f : 1.0f;
                    s16x8 v;
                    #pragma unroll
                    for (int j = 0; j < 8; j++)
                        v[j] = f2bfs(stage[(w*32 + g*8 + j)*17 + col] * qs);
                    ((s16x8*)(ws + (mat==0?QF_OFF:KF_OFF)))[(size_t)(hg*128 + bx*2 + 0)*64 + l] = v;
                }
            } else {          // V half-fragments: tc in [ch*4, ch*4+4)
                const int tcg = ch*4 + w;
                s16x4 hv;
                #pragma unroll
                for (int jj = 0; jj < 4; jj++)
                    hv[jj] = f2bfs(stage[(w*16 + col)*17 + g*4 + jj]);
                ((s16x4*)(ws + VF_OFF))[(((size_t)(bx>>1)*8 + tcg)*64 + l)*2 + (bx&1)] = hv;
            }
        } else if (sub == 6){
            // pos-terms block for n-tile bx
            float* pt   = (float*)smraw;             // [128][17]
            float* wb   = (float*)(smraw + 8704);    // [4][128]
            float* Msh  = (float*)(smraw + 10752);   // [4][9]
            float* bbar = (float*)(smraw + 10912);   // [4]
            float* kg   = (float*)(smraw + 10928);   // [4][3][16]
            float* rowt = (float*)(smraw + 11696);   // [4][16]
            float* colt = (float*)(smraw + 11952);   // [4][16]

            for (int idx = t; idx < 512; idx += 256){
                const int h = idx >> 7, c = idx & 127;
                float s = 0.f;
                #pragma unroll 8
                for (int d = 0; d < 32; d++) s += Wp2[(size_t)(h*32+d)*128 + c];
                wb[idx] = s * 0.03125f;
            }
            if (t < 4){
                float s = 0.f;
                #pragma unroll 8
                for (int d = 0; d < 32; d++) s += bp2[t*32+d];
                bbar[t] = s * 0.03125f;
            }
            {
                const int c = t & 127, hf = t >> 7;
                const float w0 = Wp1[c*3], w1 = Wp1[c*3+1], w2 = Wp1[c*3+2];
                #pragma unroll
                for (int i = 0; i < 8; i++){
                    const int nn = hf*8 + i, n = n0 + nn;
                    pt[c*17 + nn] = w0*xyz[n*3] + w1*xyz[n*3+1] + w2*xyz[n*3+2];
                }
            }
            __syncthreads();

            if (t < 36){   // M_h[a][b] = sum_c wbar * Wp1[c,a] * Wp1[c,b]
                const int h = t / 9, ab = t % 9, a = ab / 3, bb = ab % 3;
                float m = 0.f;
                for (int c = 0; c < 128; c++)
                    m += wb[h*128+c] * Wp1[c*3+a] * Wp1[c*3+bb];
                Msh[t] = m;
            }
            __syncthreads();

            if (t < 64){   // ROWT / COLT
                const int h = t >> 4, nn = t & 15;
                float ra = 0.f, ca = 0.f;
                for (int c = 0; c < 128; c++){
                    const float wv = wb[h*128+c];
                    const float p  = pt[c*17+nn];
                    const float b1 = bp1[c];
                    const float a  = fmaf(2.f*C2G, b1, 0.5f);
                    const float p2 = C2G*p*p;
                    ra += wv * (a*p + p2 + 0.5f*b1 + C2G*b1*b1);
                    ca += wv * (p2 - a*p);
                }
                rowt[h*16+nn] = ra + bbar[h];
                colt[h*16+nn] = ca;
            } else if (t < 256){   // kg[h][a][nn]
                const int u = t - 64;
                const int nn = u & 15, ha = u >> 4, h = ha / 3, a = ha % 3;
                const int n = n0 + nn;
                const float gv = Msh[h*9+a*3+0]*xyz[n*3+0]
                               + Msh[h*9+a*3+1]*xyz[n*3+1]
                               + Msh[h*9+a*3+2]*xyz[n*3+2];
                kg[(h*3+a)*16 + nn] = K2M * gv;
            }
            __syncthreads();

            // bias fragments (s=1): 8 slots via sl = w, w+4
            for (int sl = w; sl < 8; sl += 4){
                const bool isQ = sl < 4;
                const int  h   = sl & 3;
                s16x8 v;
                #pragma unroll
                for (int j = 0; j < 8; j++){
                    const int dd = g*8 + j;
                    float f;
                    if (isQ)
                        f = (dd < 3)  ? kg[(h*3+dd)*16 + col]
                          : (dd == 3) ? rowt[h*16 + col]
                          : (dd == 4) ? 1.0f : 0.0f;
                    else
                        f = (dd < 3)  ? xyz[(size_t)(n0+col)*3 + dd]
                          : (dd == 3) ? 1.0f
                          : (dd == 4) ? colt[h*16 + col] : 0.0f;
                    v[j] = f2bfs(f);
                }
                ((s16x8*)(ws + (isQ ? QF_OFF : KF_OFF)))[(size_t)(h*128 + bx*2 + 1)*64 + l] = v;
            }
        } else if (bx < 8){   // sub == 7: Wo -> bf16 linear copy (once)
            for (int i = t; i < 512; i += 256){
                const float4 w4 = ((const float4*)Wo)[bx*512 + i];
                s16x4 hv;
                hv[0] = f2bfs(w4.x); hv[1] = f2bfs(w4.y);
                hv[2] = f2bfs(w4.z); hv[3] = f2bfs(w4.w);
                ((s16x4*)(ws + WOB_OFF))[bx*512 + i] = hv;
            }
        }
    }
    cg::this_grid().sync();

    // ================= PHASE 2: attention =================
    {
        const int bx = b >> 3, by = b & 7;
        const int h = w;
        const s16x8* QFv = (const s16x8*)(ws + QF_OFF);
        const s16x8* KFv = (const s16x8*)(ws + KF_OFF);
        const s16x8* VFv = (const s16x8*)(ws + VF_OFF);

        const s16x8 bq0 = QFv[(size_t)(h*128 + bx*2 + 0)*64 + l];
        const s16x8 bq1 = QFv[(size_t)(h*128 + bx*2 + 1)*64 + l];

        f32x4 sc[8];
        #pragma unroll
        for (int tt = 0; tt < 8; tt++){
            const int mt = by*8 + tt;
            const s16x8 ak0 = KFv[(size_t)(h*128 + mt*2 + 0)*64 + l];
            const s16x8 ak1 = KFv[(size_t)(h*128 + mt*2 + 1)*64 + l];
            f32x4 c = {0.f,0.f,0.f,0.f};
            c = __builtin_amdgcn_mfma_f32_16x16x32_bf16(ak0, bq0, c, 0, 0, 0);
            c = __builtin_amdgcn_mfma_f32_16x16x32_bf16(ak1, bq1, c, 0, 0, 0);
            sc[tt] = c;
        }

        float mx = -3.4e38f;
        #pragma unroll
        for (int tt = 0; tt < 8; tt++)
            #pragma unroll
            for (int r = 0; r < 4; r++) mx = fmaxf(mx, sc[tt][r]);
        mx = fmaxf(mx, __shfl_xor(mx, 16, 64));
        mx = fmaxf(mx, __shfl_xor(mx, 32, 64));

        float sum = 0.f;
        #pragma unroll
        for (int tt = 0; tt < 8; tt++)
            #pragma unroll
            for (int r = 0; r < 4; r++){
                const float e = __builtin_amdgcn_exp2f((sc[tt][r] - mx)*LOG2E);
                sc[tt][r] = e;
                sum += e;
            }
        sum += __shfl_xor(sum, 16, 64);
        sum += __shfl_xor(sum, 32, 64);

        if (l < 16){
            ws[PMAX_OFF + (size_t)(by*4 + h)*1024 + bx*16 + l] = mx;
            ws[PSUM_OFF + (size_t)(by*4 + h)*1024 + bx*16 + l] = sum;
        }

        s16x8 pb[4];
        #pragma unroll
        for (int s = 0; s < 4; s++){
            s16x8 bb;
            #pragma unroll
            for (int r = 0; r < 4; r++){
                bb[r]   = f2bfs(sc[2*s][r]);
                bb[4+r] = f2bfs(sc[2*s+1][r]);
            }
            pb[s] = bb;
        }

        f32x4 o0 = {0.f,0.f,0.f,0.f}, o1 = {0.f,0.f,0.f,0.f};
        #pragma unroll
        for (int s = 0; s < 4; s++){
            const s16x8 av0 = VFv[(size_t)((by*4 + s)*8 + 2*h    )*64 + l];
            const s16x8 av1 = VFv[(size_t)((by*4 + s)*8 + 2*h + 1)*64 + l];
            o0 = __builtin_amdgcn_mfma_f32_16x16x32_bf16(av0, pb[s], o0, 0, 0, 0);
            o1 = __builtin_amdgcn_mfma_f32_16x16x32_bf16(av1, pb[s], o1, 0, 0, 0);
        }
        const size_t base = PACC_OFF + (size_t)(by*1024 + bx*16 + col)*128;
        *(f32x4*)&ws[base + (2*h    )*16 + g*4] = o0;
        *(f32x4*)&ws[base + (2*h + 1)*16 + g*4] = o1;
    }
    cg::this_grid().sync();

    // ================= PHASE 3: combine + Wo + residual + LN =================
    if (b < 256){
        const int n0 = b * 4;
        ushort* wbf  = (ushort*)smraw;             // [128][130] bf16 Wo
        float* alds  = (float*)(smraw + 33280);    // [128k][4nn] / later [4nn][128c]
        float* redb  = (float*)(smraw + 35328);    // [2][128][4]
        float* wcomb = (float*)(smraw + 39424);    // [8][16]
        float* stats = (float*)(smraw + 39936);    // [8]

        for (int i = t; i < 4096; i += 256){
            const s16x4 hv = ((const s16x4*)(ws + WOB_OFF))[i];
            const int c = (i*4) >> 7, k = (i*4) & 127;
            wbf[c*130+k+0] = (ushort)hv[0];
            wbf[c*130+k+1] = (ushort)hv[1];
            wbf[c*130+k+2] = (ushort)hv[2];
            wbf[c*130+k+3] = (ushort)hv[3];
        }
        if (t < 16){   // combine weights per (h, nn)
            const int h = t >> 2, nn = t & 3;
            float pm[8]; float mx = -3.4e38f;
            #pragma unroll
            for (int k = 0; k < 8; k++){
                pm[k] = ws[PMAX_OFF + (size_t)(k*4 + h)*1024 + n0 + nn];
                mx = fmaxf(mx, pm[k]);
            }
            float lam[8]; float den = 0.f;
            #pragma unroll
            for (int k = 0; k < 8; k++){
                lam[k] = __builtin_amdgcn_exp2f((pm[k] - mx)*LOG2E);
                den = fmaf(lam[k], ws[PSUM_OFF + (size_t)(k*4 + h)*1024 + n0 + nn], den);
            }
            const float rd = __builtin_amdgcn_rcpf(den);
            #pragma unroll
            for (int k = 0; k < 8; k++) wcomb[k*16 + t] = lam[k]*rd;
        }
        __syncthreads();

        {   // combine PACC -> alds[k-channel][nn]: 2 (c,nn) per thread
            const int c = t & 127, q2 = t >> 7;
            #pragma unroll
            for (int j = 0; j < 2; j++){
                const int nn = q2*2 + j;
                float num = 0.f;
                #pragma unroll
                for (int k = 0; k < 8; k++)
                    num = fmaf(wcomb[k*16 + (c>>5)*4 + nn],
                               ws[PACC_OFF + (size_t)(k*1024 + n0 + nn)*128 + c], num);
                alds[c*4 + nn] = num;
            }
        }
        __syncthreads();

        {   // split-k Wo GEMM: thread (c, kh), 4 nn each
            const int c = t & 127, kh = t >> 7;
            float a4[4] = {0.f, 0.f, 0.f, 0.f};
            const int kb = kh*64;
            #pragma unroll 4
            for (int kk = 0; kk < 64; kk++){
                const int k = kb + kk;
                const float wv = bf2f(wbf[c*130 + k]);
                const float4 av = *(const float4*)&alds[k*4];
                a4[0] = fmaf(wv, av.x, a4[0]);
                a4[1] = fmaf(wv, av.y, a4[1]);
                a4[2] = fmaf(wv, av.z, a4[2]);
                a4[3] = fmaf(wv, av.w, a4[3]);
            }
            *(float4*)&redb[((size_t)kh*128 + c)*4] =
                make_float4(a4[0], a4[1], a4[2], a4[3]);
        }
        __syncthreads();

        // fold halves + bias + residual; lnb reuses alds as [nn][c]
        float accv[2];
        const int c = t & 127, q2 = t >> 7;
        {
            const float bov = bo[c];
            #pragma unroll
            for (int j = 0; j < 2; j++){
                const int nn = q2*2 + j;
                const float v = redb[(size_t)c*4 + nn] + redb[(size_t)(128 + c)*4 + nn]
                              + bov + x[(size_t)c*1024 + n0 + nn];
                accv[j] = v;
                alds[nn*128 + c] = v;
            }
        }
        __syncthreads();

        {   // LN stats: wave w owns row w
            const float v0 = alds[w*128 + l];
            const float v1 = alds[w*128 + 64 + l];
            const float s  = wave_sum64(v0 + v1);
            const float qq = wave_sum64(fmaf(v0, v0, v1*v1));
            if (l == 0){
                const float mu  = s * 0.0078125f;
                const float var = qq * 0.0078125f - mu*mu;
                stats[w]     = mu;
                stats[4 + w] = rsqrtf(var + 1e-5f);
            }
        }
        __syncthreads();

        {
            const float gm = gamma[c], bt = beta[c];
            const int nn0 = q2*2;
            float2 o2;
            o2.x = (accv[0] - stats[nn0])   * stats[4 + nn0]   * gm + bt;
            o2.y = (accv[1] - stats[nn0+1]) * stats[4 + nn0+1] * gm + bt;
            *(float2*)(out + (size_t)c*1024 + n0 + nn0) = o2;
        }
    }
}

extern "C" void kernel_launch(void* const* d_in, const int* in_sizes, int n_in,
                              void* d_out, int out_size, void* d_ws, size_t ws_size,
                              hipStream_t stream)
{
    const float* x     = (const float*)d_in[0];
    const float* xyz   = (const float*)d_in[1];
    const float* Wq    = (const float*)d_in[2];
    const float* Wk    = (const float*)d_in[3];
    const float* Wv    = (const float*)d_in[4];
    const float* Wp1   = (const float*)d_in[5];
    const float* bp1   = (const float*)d_in[6];
    const float* Wp2   = (const float*)d_in[7];
    const float* bp2   = (const float*)d_in[8];
    const float* Wo    = (const float*)d_in[9];
    const float* bo    = (const float*)d_in[10];
    const float* gamma = (const float*)d_in[11];
    const float* beta  = (const float*)d_in[12];
    float* ws  = (float*)d_ws;
    float* out = (float*)d_out;

    void* args[] = {
        (void*)&x, (void*)&xyz, (void*)&Wq, (void*)&Wk, (void*)&Wv,
        (void*)&Wp1, (void*)&bp1, (void*)&Wp2, (void*)&bp2, (void*)&Wo,
        (void*)&bo, (void*)&gamma, (void*)&beta, (void*)&ws, (void*)&out
    };
    hipLaunchCooperativeKernel(reinterpret_cast<void*>(k_fused),
                               dim3(512), dim3(256), args, 0, stream);
}

// Round 12
// 24.788 us; speedup vs baseline: 6.3754x; 6.3754x over previous
//
#include <hip/hip_runtime.h>
#include <hip/hip_bf16.h>

#define LOG2E 1.44269504088896340736f
#define C2G   0.39894228040143267794f   // 1/sqrt(2*pi)
#define K2M  -0.79788456080286535588f   // -2*C2G

typedef __attribute__((ext_vector_type(4))) float f32x4;
typedef __attribute__((ext_vector_type(8))) short s16x8;
typedef __attribute__((ext_vector_type(4))) short s16x4;

// ---------------- workspace layout (float offsets) ----------------
static constexpr size_t QF_OFF  = 0;        // [4h][64nt][2s][64l][8j] bf16
static constexpr size_t KF_OFF  = 131072;   // same shape (m-tiles)
static constexpr size_t VF_OFF  = 262144;   // [32ks][8tc][64l][8j] bf16
static constexpr size_t AOT_OFF = 327680;   // bf16 [1024 n][128 c] = 65536 ush
// total = 360,448 floats = 1.38 MB

__device__ __forceinline__ short f2bfs(float f){
    __hip_bfloat16 h = __float2bfloat16(f);
    return __builtin_bit_cast(short, h);
}
__device__ __forceinline__ float bf2f(unsigned short u){
    return __builtin_bit_cast(float, ((unsigned)u) << 16);
}
__device__ __forceinline__ float wave_sum64(float v){
    #pragma unroll
    for (int m = 32; m >= 1; m >>= 1) v += __shfl_xor(v, m, 64);
    return v;
}

// ---------------- kernel 1: projections + pos terms -> bf16 fragments ----
// grid (64, 4), block 512: x = n-tile of 16, y = mat (0=Q,1=K,2=V,3=pos).
// (verbatim R9) k-loop split across wave-halves. Fragment k-bijections:
//   scores g(l,j) = (l>>4)*8 + j ; PV f(l,j) = (l>>4)*4 + (j&3) + 16*(j>>2)
__global__ __launch_bounds__(512) void k_prep(
    const float* __restrict__ x, const float* __restrict__ xyz,
    const float* __restrict__ Wq, const float* __restrict__ Wk,
    const float* __restrict__ Wv, const float* __restrict__ Wp1,
    const float* __restrict__ bp1, const float* __restrict__ Wp2,
    const float* __restrict__ bp2, float* __restrict__ ws)
{
    __shared__ ushort wbf[128*130];   // W bf16 [c][k] pitch 130 (33KB)
    __shared__ float  xlds[128*16];   // x [k][n16] (8KB)
    __shared__ float  st0[128*17];    // half-sum kh=0 [c][nn] (mat3: pt)
    __shared__ float  st1[128*17];    // half-sum kh=1 (mat3: scratch)
    const int t   = threadIdx.x;
    const int mat = blockIdx.y;
    const int bx  = blockIdx.x;
    const int n0  = bx * 16;
    const int l = t & 63, w = t >> 6, g = l >> 4, col = l & 15;

    if (mat == 3){
        float* pt   = st0;            // [128][17]
        float* wb   = st1;            // [4][128]
        float* Msh  = st1 + 512;      // [4][9]
        float* bbar = st1 + 548;      // [4]
        float* kg   = st1 + 552;      // [4][3][16]
        float* rowt = st1 + 744;      // [4][16]
        float* colt = st1 + 808;      // [4][16]

        {   // wb: 512 threads -> one (h,c) each
            const int h = t >> 7, c = t & 127;
            float s = 0.f;
            #pragma unroll 8
            for (int d = 0; d < 32; d++) s += Wp2[(size_t)(h*32+d)*128 + c];
            wb[t] = s * 0.03125f;
        }
        if (t < 4){
            float s = 0.f;
            #pragma unroll 8
            for (int d = 0; d < 32; d++) s += bp2[t*32+d];
            bbar[t] = s * 0.03125f;
        }
        {   // p-tile: 4 n per thread
            const int c = t & 127, ng = t >> 7;
            const float w0 = Wp1[c*3], w1 = Wp1[c*3+1], w2 = Wp1[c*3+2];
            #pragma unroll
            for (int i = 0; i < 4; i++){
                const int nn = ng*4 + i, n = n0 + nn;
                pt[c*17 + nn] = w0*xyz[n*3] + w1*xyz[n*3+1] + w2*xyz[n*3+2];
            }
        }
        __syncthreads();

        if (t < 36){   // M_h[a][b] = sum_c wbar * Wp1[c,a] * Wp1[c,b]
            const int h = t / 9, ab = t % 9, a = ab / 3, b = ab % 3;
            float m = 0.f;
            for (int c = 0; c < 128; c++)
                m += wb[h*128+c] * Wp1[c*3+a] * Wp1[c*3+b];
            Msh[t] = m;
        }
        __syncthreads();

        if (t < 64){   // ROWT / COLT
            const int h = t >> 4, nn = t & 15;
            float ra = 0.f, ca = 0.f;
            for (int c = 0; c < 128; c++){
                const float wv = wb[h*128+c];
                const float p  = pt[c*17+nn];
                const float b1 = bp1[c];
                const float a  = fmaf(2.f*C2G, b1, 0.5f);
                const float p2 = C2G*p*p;
                ra += wv * (a*p + p2 + 0.5f*b1 + C2G*b1*b1);
                ca += wv * (p2 - a*p);
            }
            rowt[h*16+nn] = ra + bbar[h];
            colt[h*16+nn] = ca;
        } else if (t < 64 + 192){   // kg[h][a][nn]
            const int u = t - 64;
            const int nn = u & 15, ha = u >> 4, h = ha / 3, a = ha % 3;
            const int n = n0 + nn;
            const float gv = Msh[h*9+a*3+0]*xyz[n*3+0]
                           + Msh[h*9+a*3+1]*xyz[n*3+1]
                           + Msh[h*9+a*3+2]*xyz[n*3+2];
            kg[(h*3+a)*16 + nn] = K2M * gv;
        }
        __syncthreads();

        // bias fragments (s=1): 8 slots, one per wave (w = 0..7)
        {
            const int  sl  = w;
            const bool isQ = sl < 4;
            const int  h   = sl & 3;
            s16x8 v;
            #pragma unroll
            for (int j = 0; j < 8; j++){
                const int dd = g*8 + j;
                float f;
                if (isQ)
                    f = (dd < 3)  ? kg[(h*3+dd)*16 + col]
                      : (dd == 3) ? rowt[h*16 + col]
                      : (dd == 4) ? 1.0f : 0.0f;
                else
                    f = (dd < 3)  ? xyz[(size_t)(n0+col)*3 + dd]
                      : (dd == 3) ? 1.0f
                      : (dd == 4) ? colt[h*16 + col] : 0.0f;
                v[j] = f2bfs(f);
            }
            ((s16x8*)(ws + (isQ ? QF_OFF : KF_OFF)))[(size_t)(h*128 + bx*2 + 1)*64 + l] = v;
        }
        return;
    }

    // ---- mats 0..2: split-k GEMM tile + fragment emit ----
    const float* W = (mat == 0) ? Wq : (mat == 1 ? Wk : Wv);
    for (int i = t; i < 16384; i += 512)
        wbf[(i>>7)*130 + (i&127)] = (ushort)f2bfs(W[i]);
    for (int i = t; i < 2048; i += 512)
        xlds[i] = x[(size_t)(i>>4)*1024 + n0 + (i&15)];
    __syncthreads();

    const int c = t & 127, ng = (t >> 7) & 1, kh = t >> 8;
    float acc[8] = {0,0,0,0,0,0,0,0};
    const int kbase = kh*64;
    #pragma unroll 4
    for (int kk = 0; kk < 64; kk++){
        const int k = kbase + kk;
        const float wv = bf2f(wbf[c*130 + k]);
        const float4 a0 = *(const float4*)&xlds[k*16 + ng*8];
        const float4 a1 = *(const float4*)&xlds[k*16 + ng*8 + 4];
        acc[0] = fmaf(wv, a0.x, acc[0]);
        acc[1] = fmaf(wv, a0.y, acc[1]);
        acc[2] = fmaf(wv, a0.z, acc[2]);
        acc[3] = fmaf(wv, a0.w, acc[3]);
        acc[4] = fmaf(wv, a1.x, acc[4]);
        acc[5] = fmaf(wv, a1.y, acc[5]);
        acc[6] = fmaf(wv, a1.z, acc[6]);
        acc[7] = fmaf(wv, a1.w, acc[7]);
    }
    float* stg = kh ? st1 : st0;
    #pragma unroll
    for (int i = 0; i < 8; i++)
        stg[c*17 + ng*8 + i] = acc[i];
    __syncthreads();

    if (w < 4){   // emission by waves 0-3 (sum the two k-halves)
        const float qs = (mat == 0) ? 0.17677669529663689f : 1.0f;  // 1/sqrt(32)
        if (mat != 2){   // Q/K s=0 fragment: wave = head
            s16x8 v;
            #pragma unroll
            for (int j = 0; j < 8; j++){
                const int idx = (w*32 + g*8 + j)*17 + col;
                v[j] = f2bfs((st0[idx] + st1[idx]) * qs);
            }
            ((s16x8*)(ws + (mat == 0 ? QF_OFF : KF_OFF)))[(size_t)(w*128 + bx*2 + 0)*64 + l] = v;
        } else {         // V half-fragments: this block = m-tile bx
            #pragma unroll
            for (int q = 0; q < 2; q++){
                const int tc = w*2 + q;
                s16x4 hv;
                #pragma unroll
                for (int jj = 0; jj < 4; jj++){
                    const int idx = (tc*16 + col)*17 + g*4 + jj;
                    hv[jj] = f2bfs(st0[idx] + st1[idx]);
                }
                ((s16x4*)(ws + VF_OFF))[(((size_t)(bx>>1)*8 + tc)*64 + l)*2 + (bx & 1)] = hv;
            }
        }
    }
}

// ---------------- kernel 2: flash attention per (n-tile, head) ----------
// grid (64, 4), block 512 = 8 waves; wave w = m-chunk w. All 8 chunks of one
// (n-tile, head) in one block: softmax combine in LDS (fp32), write final
// normalized AO (bf16 [n][c]) — no global partial round-trip.
__global__ __launch_bounds__(512) void k_attn(
    const float* __restrict__ ws_c, float* __restrict__ ws)
{
    __shared__ float smx[8*16];    // [w][n16] chunk max
    __shared__ float ssum[8*16];   // [w][n16] chunk sum
    __shared__ float sS[16];       // global denom per n
    __shared__ float so[8*544];    // [w][c32][17] scaled partials (17-pad)

    const int t = threadIdx.x, l = t & 63, w = t >> 6;
    const int bx = blockIdx.x, h = blockIdx.y;
    const int g = l >> 4, col = l & 15;

    const s16x8* QFv = (const s16x8*)(ws_c + QF_OFF);
    const s16x8* KFv = (const s16x8*)(ws_c + KF_OFF);
    const s16x8* VFv = (const s16x8*)(ws_c + VF_OFF);

    const s16x8 bq0 = QFv[(size_t)(h*128 + bx*2 + 0)*64 + l];
    const s16x8 bq1 = QFv[(size_t)(h*128 + bx*2 + 1)*64 + l];

    // scores S^T for this wave's chunk (8 m-tiles, K=64)
    f32x4 sc[8];
    #pragma unroll
    for (int tt = 0; tt < 8; tt++){
        const int mt = w*8 + tt;
        const s16x8 ak0 = KFv[(size_t)(h*128 + mt*2 + 0)*64 + l];
        const s16x8 ak1 = KFv[(size_t)(h*128 + mt*2 + 1)*64 + l];
        f32x4 c = {0.f,0.f,0.f,0.f};
        c = __builtin_amdgcn_mfma_f32_16x16x32_bf16(ak0, bq0, c, 0, 0, 0);
        c = __builtin_amdgcn_mfma_f32_16x16x32_bf16(ak1, bq1, c, 0, 0, 0);
        sc[tt] = c;
    }

    // chunk softmax partials per n (in-lane 32 + lanes l^16, l^32)
    float mx = -3.4e38f;
    #pragma unroll
    for (int tt = 0; tt < 8; tt++)
        #pragma unroll
        for (int r = 0; r < 4; r++) mx = fmaxf(mx, sc[tt][r]);
    mx = fmaxf(mx, __shfl_xor(mx, 16, 64));
    mx = fmaxf(mx, __shfl_xor(mx, 32, 64));

    float sum = 0.f;
    #pragma unroll
    for (int tt = 0; tt < 8; tt++)
        #pragma unroll
        for (int r = 0; r < 4; r++){
            const float e = __builtin_amdgcn_exp2f((sc[tt][r] - mx)*LOG2E);
            sc[tt][r] = e;
            sum += e;
        }
    sum += __shfl_xor(sum, 16, 64);
    sum += __shfl_xor(sum, 32, 64);

    if (l < 16){
        smx[w*16 + col]  = mx;
        ssum[w*16 + col] = sum;
    }

    // pack P as PV B-fragments
    s16x8 pb[4];
    #pragma unroll
    for (int s = 0; s < 4; s++){
        s16x8 b;
        #pragma unroll
        for (int r = 0; r < 4; r++){
            b[r]   = f2bfs(sc[2*s][r]);
            b[4+r] = f2bfs(sc[2*s+1][r]);
        }
        pb[s] = b;
    }

    // PV for this head's channels tc = 2h, 2h+1
    f32x4 o0 = {0.f,0.f,0.f,0.f}, o1 = {0.f,0.f,0.f,0.f};
    #pragma unroll
    for (int s = 0; s < 4; s++){
        const s16x8 av0 = VFv[(size_t)((w*4 + s)*8 + 2*h    )*64 + l];
        const s16x8 av1 = VFv[(size_t)((w*4 + s)*8 + 2*h + 1)*64 + l];
        o0 = __builtin_amdgcn_mfma_f32_16x16x32_bf16(av0, pb[s], o0, 0, 0, 0);
        o1 = __builtin_amdgcn_mfma_f32_16x16x32_bf16(av1, pb[s], o1, 0, 0, 0);
    }
    __syncthreads();   // all smx/ssum visible

    // global max per n; this wave's rescale factor
    float M = -3.4e38f;
    #pragma unroll
    for (int k = 0; k < 8; k++) M = fmaxf(M, smx[k*16 + col]);
    const float lam = __builtin_amdgcn_exp2f((mx - M)*LOG2E);
    if (w == 0 && l < 16){
        float S = 0.f;
        #pragma unroll
        for (int k = 0; k < 8; k++)
            S = fmaf(__builtin_amdgcn_exp2f((smx[k*16 + col] - M)*LOG2E),
                     ssum[k*16 + col], S);
        sS[col] = S;
    }
    // scaled partials to my slot: c_local = (o1?16:0) + g*4 + r, n = col
    #pragma unroll
    for (int r = 0; r < 4; r++){
        so[w*544 + (g*4 + r)*17 + col]        = o0[r]*lam;
        so[w*544 + (16 + g*4 + r)*17 + col]   = o1[r]*lam;
    }
    __syncthreads();

    // final: 512 threads, element (c_local = t&31, n = t>>5)
    {
        const int cl = t & 31, nn = t >> 5;
        float a = 0.f;
        #pragma unroll
        for (int k = 0; k < 8; k++) a += so[k*544 + cl*17 + nn];
        a *= __builtin_amdgcn_rcpf(sS[nn]);
        ((ushort*)(ws + AOT_OFF))[(size_t)(bx*16 + nn)*128 + h*32 + cl] =
            (ushort)f2bfs(a);
    }
}

// ---------------- kernel 3: Wo matmul + residual + LayerNorm -------------
// grid (256), block 512: n-tile of 4, k-loop split across wave-halves.
// (R9 structure, combine front-end replaced by direct AO read.)
__global__ __launch_bounds__(512) void k_final(
    const float* __restrict__ Wo, const float* __restrict__ bo,
    const float* __restrict__ x, const float* __restrict__ gamma,
    const float* __restrict__ beta, const float* __restrict__ ws,
    float* __restrict__ out)
{
    __shared__ ushort wbf[128*130];   // Wo bf16 [c][k] pitch 130 (33KB)
    __shared__ float alds[128*4];     // [k][nn] then reused as [nn][c]
    __shared__ float redb[2*128*4];   // [kh][c][nn]
    __shared__ float stats[8];        // mu[4], rstd[4]
    const int t  = threadIdx.x;
    const int n0 = blockIdx.x * 4;

    for (int i = t; i < 16384; i += 512)
        wbf[(i>>7)*130 + (i&127)] = (ushort)f2bfs(Wo[i]);
    {   // AO tile: 512 threads, one (c, nn) each (coalesced bf16 read)
        const int c = t & 127, nn = t >> 7;
        alds[c*4 + nn] =
            bf2f(((const ushort*)(ws + AOT_OFF))[(size_t)(n0 + nn)*128 + c]);
    }
    __syncthreads();

    // split-k Wo GEMM: thread (c, q, kh); nn = q*2+{0,1}
    const int c = t & 127, q = (t >> 7) & 1, kh = t >> 8;
    float acc2[2] = {0.f, 0.f};
    const int kbase = kh*64;
    #pragma unroll 4
    for (int kk = 0; kk < 64; kk++){
        const int k = kbase + kk;
        const float  wv = bf2f(wbf[c*130 + k]);
        const float2 a2 = *(const float2*)&alds[k*4 + q*2];
        acc2[0] = fmaf(wv, a2.x, acc2[0]);
        acc2[1] = fmaf(wv, a2.y, acc2[1]);
    }
    redb[(kh*128 + c)*4 + q*2 + 0] = acc2[0];
    redb[(kh*128 + c)*4 + q*2 + 1] = acc2[1];
    __syncthreads();

    // reduce halves + bias + residual (threads 0..255: one (c, q) pair)
    float accv[2];
    if (t < 256){
        const int cc = t & 127, qq = t >> 7;
        const float bov = bo[cc];
        #pragma unroll
        for (int r = 0; r < 2; r++){
            const int nn = qq*2 + r;
            const float v = redb[(0*128 + cc)*4 + nn] + redb[(128 + cc)*4 + nn]
                          + bov + x[(size_t)cc*1024 + n0 + nn];
            accv[r] = v;
            alds[nn*128 + cc] = v;   // lnb [nn][c]
        }
    }
    __syncthreads();

    {   // LN stats: waves 0-3, wave w owns row w
        const int lane = t & 63, w = t >> 6;
        if (w < 4){
            const float v0 = alds[w*128 + lane];
            const float v1 = alds[w*128 + 64 + lane];
            const float s  = wave_sum64(v0 + v1);
            const float qq2 = wave_sum64(fmaf(v0, v0, v1*v1));
            if (lane == 0){
                const float mu  = s * 0.0078125f;
                const float var = qq2 * 0.0078125f - mu*mu;
                stats[w]     = mu;
                stats[4 + w] = rsqrtf(var + 1e-5f);
            }
        }
    }
    __syncthreads();

    if (t < 256){
        const int cc = t & 127, qq = t >> 7;
        const float g = gamma[cc], b = beta[cc];
        const int nn0 = qq*2;
        float2 o2;
        o2.x = (accv[0] - stats[nn0])   * stats[4 + nn0]   * g + b;
        o2.y = (accv[1] - stats[nn0+1]) * stats[4 + nn0+1] * g + b;
        *(float2*)(out + (size_t)cc*1024 + n0 + nn0) = o2;
    }
}

extern "C" void kernel_launch(void* const* d_in, const int* in_sizes, int n_in,
                              void* d_out, int out_size, void* d_ws, size_t ws_size,
                              hipStream_t stream)
{
    const float* x     = (const float*)d_in[0];
    const float* xyz   = (const float*)d_in[1];
    const float* Wq    = (const float*)d_in[2];
    const float* Wk    = (const float*)d_in[3];
    const float* Wv    = (const float*)d_in[4];
    const float* Wp1   = (const float*)d_in[5];
    const float* bp1   = (const float*)d_in[6];
    const float* Wp2   = (const float*)d_in[7];
    const float* bp2   = (const float*)d_in[8];
    const float* Wo    = (const float*)d_in[9];
    const float* bo    = (const float*)d_in[10];
    const float* gamma = (const float*)d_in[11];
    const float* beta  = (const float*)d_in[12];
    float* ws  = (float*)d_ws;
    float* out = (float*)d_out;

    hipLaunchKernelGGL(k_prep,  dim3(64, 4), dim3(512), 0, stream,
                       x, xyz, Wq, Wk, Wv, Wp1, bp1, Wp2, bp2, ws);
    hipLaunchKernelGGL(k_attn,  dim3(64, 4), dim3(512), 0, stream, ws, ws);
    hipLaunchKernelGGL(k_final, dim3(256),   dim3(512), 0, stream,
                       Wo, bo, x, gamma, beta, ws, out);
}

// Round 13
// 24.661 us; speedup vs baseline: 6.4080x; 1.0051x over previous
//
#include <hip/hip_runtime.h>
#include <hip/hip_bf16.h>

#define LOG2E 1.44269504088896340736f
#define C2G   0.39894228040143267794f   // 1/sqrt(2*pi)
#define K2M  -0.79788456080286535588f   // -2*C2G

typedef __attribute__((ext_vector_type(4))) float f32x4;
typedef __attribute__((ext_vector_type(8))) short s16x8;
typedef __attribute__((ext_vector_type(4))) short s16x4;

// ---------------- workspace layout (float offsets) ----------------
static constexpr size_t QF_OFF  = 0;        // [4h][64nt][2s][64l][8j] bf16
static constexpr size_t KF_OFF  = 131072;   // same shape (m-tiles)
static constexpr size_t VF_OFF  = 262144;   // [32ks][8tc][64l][8j] bf16
static constexpr size_t AOT_OFF = 327680;   // bf16 [1024 n][128 c] = 65536 ush
static constexpr size_t WOB_OFF = 360448;   // bf16 Wo linear [c*128+k] = 16384 ush
// total = 368,640 floats = 1.41 MB

__device__ __forceinline__ short f2bfs(float f){
    __hip_bfloat16 h = __float2bfloat16(f);
    return __builtin_bit_cast(short, h);
}
__device__ __forceinline__ float bf2f(unsigned short u){
    return __builtin_bit_cast(float, ((unsigned)u) << 16);
}
__device__ __forceinline__ float wave_sum64(float v){
    #pragma unroll
    for (int m = 32; m >= 1; m >>= 1) v += __shfl_xor(v, m, 64);
    return v;
}

// ---------------- kernel 1: projections + pos terms -> bf16 fragments ----
// grid (64, 4), block 512: x = n-tile of 16, y = mat (0=Q,1=K,2=V,3=pos).
// k-loop split across wave-halves. Fragment k-bijections (HW-validated):
//   scores g(l,j) = (l>>4)*8 + j ; PV f(l,j) = (l>>4)*4 + (j&3) + 16*(j>>2)
__global__ __launch_bounds__(512) void k_prep(
    const float* __restrict__ x, const float* __restrict__ xyz,
    const float* __restrict__ Wq, const float* __restrict__ Wk,
    const float* __restrict__ Wv, const float* __restrict__ Wp1,
    const float* __restrict__ bp1, const float* __restrict__ Wp2,
    const float* __restrict__ bp2, const float* __restrict__ Wo,
    float* __restrict__ ws)
{
    __shared__ ushort wbf[128*130];   // W bf16 [c][k] pitch 130 (33KB)
    __shared__ float  xlds[128*16];   // x [k][n16] (8KB)
    __shared__ float  st0[128*17];    // half-sum kh=0 [c][nn] (mat3: pt)
    __shared__ float  st1[128*17];    // half-sum kh=1 (mat3: scratch)
    const int t   = threadIdx.x;
    const int mat = blockIdx.y;
    const int bx  = blockIdx.x;
    const int n0  = bx * 16;
    const int l = t & 63, w = t >> 6, g = l >> 4, col = l & 15;

    if (mat == 3){
        // Wo -> bf16 copy (once; consumed by k_final next dispatch)
        if (bx < 8){
            const float4 w4 = ((const float4*)Wo)[bx*512 + t];
            s16x4 hv;
            hv[0] = f2bfs(w4.x); hv[1] = f2bfs(w4.y);
            hv[2] = f2bfs(w4.z); hv[3] = f2bfs(w4.w);
            ((s16x4*)(ws + WOB_OFF))[bx*512 + t] = hv;
        }

        float* pt   = st0;            // [128][17]
        float* wb   = st1;            // [4][128]
        float* Msh  = st1 + 512;      // [4][9]
        float* bbar = st1 + 548;      // [4]
        float* kg   = st1 + 552;      // [4][3][16]
        float* rowt = st1 + 744;      // [4][16]
        float* colt = st1 + 808;      // [4][16]

        {   // wb: 512 threads -> one (h,c) each
            const int h = t >> 7, c = t & 127;
            float s = 0.f;
            #pragma unroll 8
            for (int d = 0; d < 32; d++) s += Wp2[(size_t)(h*32+d)*128 + c];
            wb[t] = s * 0.03125f;
        }
        if (t < 4){
            float s = 0.f;
            #pragma unroll 8
            for (int d = 0; d < 32; d++) s += bp2[t*32+d];
            bbar[t] = s * 0.03125f;
        }
        {   // p-tile: 4 n per thread
            const int c = t & 127, ng = t >> 7;
            const float w0 = Wp1[c*3], w1 = Wp1[c*3+1], w2 = Wp1[c*3+2];
            #pragma unroll
            for (int i = 0; i < 4; i++){
                const int nn = ng*4 + i, n = n0 + nn;
                pt[c*17 + nn] = w0*xyz[n*3] + w1*xyz[n*3+1] + w2*xyz[n*3+2];
            }
        }
        __syncthreads();

        if (t < 36){   // M_h[a][b] = sum_c wbar * Wp1[c,a] * Wp1[c,b]
            const int h = t / 9, ab = t % 9, a = ab / 3, b = ab % 3;
            float m = 0.f;
            for (int c = 0; c < 128; c++)
                m += wb[h*128+c] * Wp1[c*3+a] * Wp1[c*3+b];
            Msh[t] = m;
        }
        __syncthreads();

        if (t < 64){   // ROWT / COLT
            const int h = t >> 4, nn = t & 15;
            float ra = 0.f, ca = 0.f;
            for (int c = 0; c < 128; c++){
                const float wv = wb[h*128+c];
                const float p  = pt[c*17+nn];
                const float b1 = bp1[c];
                const float a  = fmaf(2.f*C2G, b1, 0.5f);
                const float p2 = C2G*p*p;
                ra += wv * (a*p + p2 + 0.5f*b1 + C2G*b1*b1);
                ca += wv * (p2 - a*p);
            }
            rowt[h*16+nn] = ra + bbar[h];
            colt[h*16+nn] = ca;
        } else if (t < 64 + 192){   // kg[h][a][nn]
            const int u = t - 64;
            const int nn = u & 15, ha = u >> 4, h = ha / 3, a = ha % 3;
            const int n = n0 + nn;
            const float gv = Msh[h*9+a*3+0]*xyz[n*3+0]
                           + Msh[h*9+a*3+1]*xyz[n*3+1]
                           + Msh[h*9+a*3+2]*xyz[n*3+2];
            kg[(h*3+a)*16 + nn] = K2M * gv;
        }
        __syncthreads();

        // bias fragments (s=1): 8 slots, one per wave (w = 0..7)
        {
            const int  sl  = w;
            const bool isQ = sl < 4;
            const int  h   = sl & 3;
            s16x8 v;
            #pragma unroll
            for (int j = 0; j < 8; j++){
                const int dd = g*8 + j;
                float f;
                if (isQ)
                    f = (dd < 3)  ? kg[(h*3+dd)*16 + col]
                      : (dd == 3) ? rowt[h*16 + col]
                      : (dd == 4) ? 1.0f : 0.0f;
                else
                    f = (dd < 3)  ? xyz[(size_t)(n0+col)*3 + dd]
                      : (dd == 3) ? 1.0f
                      : (dd == 4) ? colt[h*16 + col] : 0.0f;
                v[j] = f2bfs(f);
            }
            ((s16x8*)(ws + (isQ ? QF_OFF : KF_OFF)))[(size_t)(h*128 + bx*2 + 1)*64 + l] = v;
        }
        return;
    }

    // ---- mats 0..2: split-k GEMM tile + fragment emit ----
    const float* W = (mat == 0) ? Wq : (mat == 1 ? Wk : Wv);
    for (int i = t; i < 4096; i += 512){   // float4-vectorized W staging
        const float4 w4 = ((const float4*)W)[i];
        const int c = i >> 5, k = (i*4) & 127;
        wbf[c*130 + k + 0] = (ushort)f2bfs(w4.x);
        wbf[c*130 + k + 1] = (ushort)f2bfs(w4.y);
        wbf[c*130 + k + 2] = (ushort)f2bfs(w4.z);
        wbf[c*130 + k + 3] = (ushort)f2bfs(w4.w);
    }
    {   // float4-vectorized x-tile staging: 512 float4s, one per thread
        const int row = t >> 2, part = t & 3;
        *(float4*)&xlds[row*16 + part*4] =
            *(const float4*)(x + (size_t)row*1024 + n0 + part*4);
    }
    __syncthreads();

    const int c = t & 127, ng = (t >> 7) & 1, kh = t >> 8;
    float acc[8] = {0,0,0,0,0,0,0,0};
    const int kbase = kh*64;
    #pragma unroll 4
    for (int kk = 0; kk < 64; kk++){
        const int k = kbase + kk;
        const float wv = bf2f(wbf[c*130 + k]);
        const float4 a0 = *(const float4*)&xlds[k*16 + ng*8];
        const float4 a1 = *(const float4*)&xlds[k*16 + ng*8 + 4];
        acc[0] = fmaf(wv, a0.x, acc[0]);
        acc[1] = fmaf(wv, a0.y, acc[1]);
        acc[2] = fmaf(wv, a0.z, acc[2]);
        acc[3] = fmaf(wv, a0.w, acc[3]);
        acc[4] = fmaf(wv, a1.x, acc[4]);
        acc[5] = fmaf(wv, a1.y, acc[5]);
        acc[6] = fmaf(wv, a1.z, acc[6]);
        acc[7] = fmaf(wv, a1.w, acc[7]);
    }
    float* stg = kh ? st1 : st0;
    #pragma unroll
    for (int i = 0; i < 8; i++)
        stg[c*17 + ng*8 + i] = acc[i];
    __syncthreads();

    if (w < 4){   // emission by waves 0-3 (sum the two k-halves)
        const float qs = (mat == 0) ? 0.17677669529663689f : 1.0f;  // 1/sqrt(32)
        if (mat != 2){   // Q/K s=0 fragment: wave = head
            s16x8 v;
            #pragma unroll
            for (int j = 0; j < 8; j++){
                const int idx = (w*32 + g*8 + j)*17 + col;
                v[j] = f2bfs((st0[idx] + st1[idx]) * qs);
            }
            ((s16x8*)(ws + (mat == 0 ? QF_OFF : KF_OFF)))[(size_t)(w*128 + bx*2 + 0)*64 + l] = v;
        } else {         // V half-fragments: this block = m-tile bx
            #pragma unroll
            for (int q = 0; q < 2; q++){
                const int tc = w*2 + q;
                s16x4 hv;
                #pragma unroll
                for (int jj = 0; jj < 4; jj++){
                    const int idx = (tc*16 + col)*17 + g*4 + jj;
                    hv[jj] = f2bfs(st0[idx] + st1[idx]);
                }
                ((s16x4*)(ws + VF_OFF))[(((size_t)(bx>>1)*8 + tc)*64 + l)*2 + (bx & 1)] = hv;
            }
        }
    }
}

// ---------------- kernel 2: flash attention per (n-tile, head) ----------
// grid (64, 4), block 512 = 8 waves; wave w = m-chunk w. All 8 chunks of one
// (n-tile, head) in one block: softmax combine in LDS (fp32), write final
// normalized AO (bf16 [n][c]). (verbatim R12)
__global__ __launch_bounds__(512) void k_attn(
    const float* __restrict__ ws_c, float* __restrict__ ws)
{
    __shared__ float smx[8*16];    // [w][n16] chunk max
    __shared__ float ssum[8*16];   // [w][n16] chunk sum
    __shared__ float sS[16];       // global denom per n
    __shared__ float so[8*544];    // [w][c32][17] scaled partials (17-pad)

    const int t = threadIdx.x, l = t & 63, w = t >> 6;
    const int bx = blockIdx.x, h = blockIdx.y;
    const int g = l >> 4, col = l & 15;

    const s16x8* QFv = (const s16x8*)(ws_c + QF_OFF);
    const s16x8* KFv = (const s16x8*)(ws_c + KF_OFF);
    const s16x8* VFv = (const s16x8*)(ws_c + VF_OFF);

    const s16x8 bq0 = QFv[(size_t)(h*128 + bx*2 + 0)*64 + l];
    const s16x8 bq1 = QFv[(size_t)(h*128 + bx*2 + 1)*64 + l];

    // scores S^T for this wave's chunk (8 m-tiles, K=64)
    f32x4 sc[8];
    #pragma unroll
    for (int tt = 0; tt < 8; tt++){
        const int mt = w*8 + tt;
        const s16x8 ak0 = KFv[(size_t)(h*128 + mt*2 + 0)*64 + l];
        const s16x8 ak1 = KFv[(size_t)(h*128 + mt*2 + 1)*64 + l];
        f32x4 c = {0.f,0.f,0.f,0.f};
        c = __builtin_amdgcn_mfma_f32_16x16x32_bf16(ak0, bq0, c, 0, 0, 0);
        c = __builtin_amdgcn_mfma_f32_16x16x32_bf16(ak1, bq1, c, 0, 0, 0);
        sc[tt] = c;
    }

    // chunk softmax partials per n (in-lane 32 + lanes l^16, l^32)
    float mx = -3.4e38f;
    #pragma unroll
    for (int tt = 0; tt < 8; tt++)
        #pragma unroll
        for (int r = 0; r < 4; r++) mx = fmaxf(mx, sc[tt][r]);
    mx = fmaxf(mx, __shfl_xor(mx, 16, 64));
    mx = fmaxf(mx, __shfl_xor(mx, 32, 64));

    float sum = 0.f;
    #pragma unroll
    for (int tt = 0; tt < 8; tt++)
        #pragma unroll
        for (int r = 0; r < 4; r++){
            const float e = __builtin_amdgcn_exp2f((sc[tt][r] - mx)*LOG2E);
            sc[tt][r] = e;
            sum += e;
        }
    sum += __shfl_xor(sum, 16, 64);
    sum += __shfl_xor(sum, 32, 64);

    if (l < 16){
        smx[w*16 + col]  = mx;
        ssum[w*16 + col] = sum;
    }

    // pack P as PV B-fragments
    s16x8 pb[4];
    #pragma unroll
    for (int s = 0; s < 4; s++){
        s16x8 b;
        #pragma unroll
        for (int r = 0; r < 4; r++){
            b[r]   = f2bfs(sc[2*s][r]);
            b[4+r] = f2bfs(sc[2*s+1][r]);
        }
        pb[s] = b;
    }

    // PV for this head's channels tc = 2h, 2h+1
    f32x4 o0 = {0.f,0.f,0.f,0.f}, o1 = {0.f,0.f,0.f,0.f};
    #pragma unroll
    for (int s = 0; s < 4; s++){
        const s16x8 av0 = VFv[(size_t)((w*4 + s)*8 + 2*h    )*64 + l];
        const s16x8 av1 = VFv[(size_t)((w*4 + s)*8 + 2*h + 1)*64 + l];
        o0 = __builtin_amdgcn_mfma_f32_16x16x32_bf16(av0, pb[s], o0, 0, 0, 0);
        o1 = __builtin_amdgcn_mfma_f32_16x16x32_bf16(av1, pb[s], o1, 0, 0, 0);
    }
    __syncthreads();   // all smx/ssum visible

    // global max per n; this wave's rescale factor
    float M = -3.4e38f;
    #pragma unroll
    for (int k = 0; k < 8; k++) M = fmaxf(M, smx[k*16 + col]);
    const float lam = __builtin_amdgcn_exp2f((mx - M)*LOG2E);
    if (w == 0 && l < 16){
        float S = 0.f;
        #pragma unroll
        for (int k = 0; k < 8; k++)
            S = fmaf(__builtin_amdgcn_exp2f((smx[k*16 + col] - M)*LOG2E),
                     ssum[k*16 + col], S);
        sS[col] = S;
    }
    // scaled partials to my slot: c_local = (o1?16:0) + g*4 + r, n = col
    #pragma unroll
    for (int r = 0; r < 4; r++){
        so[w*544 + (g*4 + r)*17 + col]        = o0[r]*lam;
        so[w*544 + (16 + g*4 + r)*17 + col]   = o1[r]*lam;
    }
    __syncthreads();

    // final: 512 threads, element (c_local = t&31, n = t>>5)
    {
        const int cl = t & 31, nn = t >> 5;
        float a = 0.f;
        #pragma unroll
        for (int k = 0; k < 8; k++) a += so[k*544 + cl*17 + nn];
        a *= __builtin_amdgcn_rcpf(sS[nn]);
        ((ushort*)(ws + AOT_OFF))[(size_t)(bx*16 + nn)*128 + h*32 + cl] =
            (ushort)f2bfs(a);
    }
}

// ---------------- kernel 3: Wo matmul + residual + LayerNorm -------------
// grid (256), block 512: n-tile of 4, k-loop split across wave-halves.
// Wo staged from the prebuilt bf16 copy (no per-block fp32 reload/convert).
__global__ __launch_bounds__(512) void k_final(
    const float* __restrict__ bo, const float* __restrict__ x,
    const float* __restrict__ gamma, const float* __restrict__ beta,
    const float* __restrict__ ws, float* __restrict__ out)
{
    __shared__ ushort wbf[128*130];   // Wo bf16 [c][k] pitch 130 (33KB)
    __shared__ float alds[128*4];     // [k][nn] then reused as [nn][c]
    __shared__ float redb[2*128*4];   // [kh][c][nn]
    __shared__ float stats[8];        // mu[4], rstd[4]
    const int t  = threadIdx.x;
    const int n0 = blockIdx.x * 4;

    for (int i = t; i < 4096; i += 512){   // stage bf16 Wo: s16x4 loads
        const s16x4 hv = ((const s16x4*)(ws + WOB_OFF))[i];
        const int c = i >> 5, k = (i*4) & 127;
        wbf[c*130 + k + 0] = (ushort)hv[0];
        wbf[c*130 + k + 1] = (ushort)hv[1];
        wbf[c*130 + k + 2] = (ushort)hv[2];
        wbf[c*130 + k + 3] = (ushort)hv[3];
    }
    {   // AO tile: 512 threads, one (c, nn) each (coalesced bf16 read)
        const int c = t & 127, nn = t >> 7;
        alds[c*4 + nn] =
            bf2f(((const ushort*)(ws + AOT_OFF))[(size_t)(n0 + nn)*128 + c]);
    }
    __syncthreads();

    // split-k Wo GEMM: thread (c, q, kh); nn = q*2+{0,1}
    const int c = t & 127, q = (t >> 7) & 1, kh = t >> 8;
    float acc2[2] = {0.f, 0.f};
    const int kbase = kh*64;
    #pragma unroll 4
    for (int kk = 0; kk < 64; kk++){
        const int k = kbase + kk;
        const float  wv = bf2f(wbf[c*130 + k]);
        const float2 a2 = *(const float2*)&alds[k*4 + q*2];
        acc2[0] = fmaf(wv, a2.x, acc2[0]);
        acc2[1] = fmaf(wv, a2.y, acc2[1]);
    }
    redb[(kh*128 + c)*4 + q*2 + 0] = acc2[0];
    redb[(kh*128 + c)*4 + q*2 + 1] = acc2[1];
    __syncthreads();

    // reduce halves + bias + residual (threads 0..255: one (c, q) pair)
    float accv[2];
    if (t < 256){
        const int cc = t & 127, qq = t >> 7;
        const float bov = bo[cc];
        #pragma unroll
        for (int r = 0; r < 2; r++){
            const int nn = qq*2 + r;
            const float v = redb[(0*128 + cc)*4 + nn] + redb[(128 + cc)*4 + nn]
                          + bov + x[(size_t)cc*1024 + n0 + nn];
            accv[r] = v;
            alds[nn*128 + cc] = v;   // lnb [nn][c]
        }
    }
    __syncthreads();

    {   // LN stats: waves 0-3, wave w owns row w
        const int lane = t & 63, w = t >> 6;
        if (w < 4){
            const float v0 = alds[w*128 + lane];
            const float v1 = alds[w*128 + 64 + lane];
            const float s  = wave_sum64(v0 + v1);
            const float qq2 = wave_sum64(fmaf(v0, v0, v1*v1));
            if (lane == 0){
                const float mu  = s * 0.0078125f;
                const float var = qq2 * 0.0078125f - mu*mu;
                stats[w]     = mu;
                stats[4 + w] = rsqrtf(var + 1e-5f);
            }
        }
    }
    __syncthreads();

    if (t < 256){
        const int cc = t & 127, qq = t >> 7;
        const float g = gamma[cc], b = beta[cc];
        const int nn0 = qq*2;
        float2 o2;
        o2.x = (accv[0] - stats[nn0])   * stats[4 + nn0]   * g + b;
        o2.y = (accv[1] - stats[nn0+1]) * stats[4 + nn0+1] * g + b;
        *(float2*)(out + (size_t)cc*1024 + n0 + nn0) = o2;
    }
}

extern "C" void kernel_launch(void* const* d_in, const int* in_sizes, int n_in,
                              void* d_out, int out_size, void* d_ws, size_t ws_size,
                              hipStream_t stream)
{
    const float* x     = (const float*)d_in[0];
    const float* xyz   = (const float*)d_in[1];
    const float* Wq    = (const float*)d_in[2];
    const float* Wk    = (const float*)d_in[3];
    const float* Wv    = (const float*)d_in[4];
    const float* Wp1   = (const float*)d_in[5];
    const float* bp1   = (const float*)d_in[6];
    const float* Wp2   = (const float*)d_in[7];
    const float* bp2   = (const float*)d_in[8];
    const float* Wo    = (const float*)d_in[9];
    const float* bo    = (const float*)d_in[10];
    const float* gamma = (const float*)d_in[11];
    const float* beta  = (const float*)d_in[12];
    float* ws  = (float*)d_ws;
    float* out = (float*)d_out;

    hipLaunchKernelGGL(k_prep,  dim3(64, 4), dim3(512), 0, stream,
                       x, xyz, Wq, Wk, Wv, Wp1, bp1, Wp2, bp2, Wo, ws);
    hipLaunchKernelGGL(k_attn,  dim3(64, 4), dim3(512), 0, stream, ws, ws);
    hipLaunchKernelGGL(k_final, dim3(256),   dim3(512), 0, stream,
                       bo, x, gamma, beta, ws, out);
}

// Round 14
// 24.439 us; speedup vs baseline: 6.4663x; 1.0091x over previous
//
#include <hip/hip_runtime.h>
#include <hip/hip_bf16.h>

#define LOG2E 1.44269504088896340736f
#define C2G   0.39894228040143267794f   // 1/sqrt(2*pi)
#define K2M  -0.79788456080286535588f   // -2*C2G

typedef __attribute__((ext_vector_type(4))) float f32x4;
typedef __attribute__((ext_vector_type(8))) short s16x8;
typedef __attribute__((ext_vector_type(4))) short s16x4;

// ---------------- workspace layout (float offsets) ----------------
static constexpr size_t QF_OFF  = 0;        // [4h][64nt][2s][64l][8j] bf16
static constexpr size_t KF_OFF  = 131072;   // same shape (m-tiles)
static constexpr size_t VF_OFF  = 262144;   // [32ks][8tc][64l][8j] bf16
static constexpr size_t AOT_OFF = 327680;   // bf16 [1024 n][128 c] = 65536 ush
static constexpr size_t WOB_OFF = 360448;   // bf16 Wo linear [c*128+k] = 16384 ush
// total = 368,640 floats = 1.41 MB

__device__ __forceinline__ short f2bfs(float f){
    __hip_bfloat16 h = __float2bfloat16(f);
    return __builtin_bit_cast(short, h);
}
__device__ __forceinline__ float bf2f(unsigned short u){
    return __builtin_bit_cast(float, ((unsigned)u) << 16);
}
__device__ __forceinline__ float wave_sum64(float v){
    #pragma unroll
    for (int m = 32; m >= 1; m >>= 1) v += __shfl_xor(v, m, 64);
    return v;
}

// ---------------- kernel 1: projections + pos terms -> bf16 fragments ----
// grid (64, 4), block 512: x = n-tile of 16, y = mat (0=Q,1=K,2=V,3=pos).
// Projection GEMM now via MFMA from LDS (wave w = m-tile w):
//   A(l,j) = W[w*16 + (l&15)][s*32 + kappa], kappa(l,j) = (l>>4)*8 + j
//   B(l,j) = x[s*32 + kappa][n0 + (l&15)]   (x staged transposed bf16)
// Both are single ds_read_b128 per slot (pitch 136 ushorts = 16B-aligned).
// D: C[w*16 + (l>>4)*4 + r][n0 + (l&15)]  (HW-validated layout).
__global__ __launch_bounds__(512) void k_prep(
    const float* __restrict__ x, const float* __restrict__ xyz,
    const float* __restrict__ Wq, const float* __restrict__ Wk,
    const float* __restrict__ Wv, const float* __restrict__ Wp1,
    const float* __restrict__ bp1, const float* __restrict__ Wp2,
    const float* __restrict__ bp2, const float* __restrict__ Wo,
    float* __restrict__ ws)
{
    __shared__ ushort wbf[128*136];   // W bf16 [c][k] pitch 136 (34.8KB)
    __shared__ ushort xbfT[16*136];   // x^T bf16 [n][k] pitch 136 (4.3KB)
    __shared__ float  st[128*17];     // output tile [c][nn] (mat3: pt)
    __shared__ float  scr[1024];      // mat3 scratch
    const int t   = threadIdx.x;
    const int mat = blockIdx.y;
    const int bx  = blockIdx.x;
    const int n0  = bx * 16;
    const int l = t & 63, w = t >> 6, g = l >> 4, col = l & 15;

    if (mat == 3){
        // Wo -> bf16 copy (once; consumed by k_final next dispatch)
        if (bx < 8){
            const float4 w4 = ((const float4*)Wo)[bx*512 + t];
            s16x4 hv;
            hv[0] = f2bfs(w4.x); hv[1] = f2bfs(w4.y);
            hv[2] = f2bfs(w4.z); hv[3] = f2bfs(w4.w);
            ((s16x4*)(ws + WOB_OFF))[bx*512 + t] = hv;
        }

        float* pt   = st;             // [128][17]
        float* wb   = scr;            // [4][128]
        float* Msh  = scr + 512;      // [4][9]
        float* bbar = scr + 548;      // [4]
        float* kg   = scr + 552;      // [4][3][16]
        float* rowt = scr + 744;      // [4][16]
        float* colt = scr + 808;      // [4][16]

        {   // wb: 512 threads -> one (h,c) each
            const int h = t >> 7, c = t & 127;
            float s = 0.f;
            #pragma unroll 8
            for (int d = 0; d < 32; d++) s += Wp2[(size_t)(h*32+d)*128 + c];
            wb[t] = s * 0.03125f;
        }
        if (t < 4){
            float s = 0.f;
            #pragma unroll 8
            for (int d = 0; d < 32; d++) s += bp2[t*32+d];
            bbar[t] = s * 0.03125f;
        }
        {   // p-tile: 4 n per thread
            const int c = t & 127, ng = t >> 7;
            const float w0 = Wp1[c*3], w1 = Wp1[c*3+1], w2 = Wp1[c*3+2];
            #pragma unroll
            for (int i = 0; i < 4; i++){
                const int nn = ng*4 + i, n = n0 + nn;
                pt[c*17 + nn] = w0*xyz[n*3] + w1*xyz[n*3+1] + w2*xyz[n*3+2];
            }
        }
        __syncthreads();

        if (t < 36){   // M_h[a][b] = sum_c wbar * Wp1[c,a] * Wp1[c,b]
            const int h = t / 9, ab = t % 9, a = ab / 3, b = ab % 3;
            float m = 0.f;
            for (int c = 0; c < 128; c++)
                m += wb[h*128+c] * Wp1[c*3+a] * Wp1[c*3+b];
            Msh[t] = m;
        }
        __syncthreads();

        if (t < 64){   // ROWT / COLT
            const int h = t >> 4, nn = t & 15;
            float ra = 0.f, ca = 0.f;
            for (int c = 0; c < 128; c++){
                const float wv = wb[h*128+c];
                const float p  = pt[c*17+nn];
                const float b1 = bp1[c];
                const float a  = fmaf(2.f*C2G, b1, 0.5f);
                const float p2 = C2G*p*p;
                ra += wv * (a*p + p2 + 0.5f*b1 + C2G*b1*b1);
                ca += wv * (p2 - a*p);
            }
            rowt[h*16+nn] = ra + bbar[h];
            colt[h*16+nn] = ca;
        } else if (t < 64 + 192){   // kg[h][a][nn]
            const int u = t - 64;
            const int nn = u & 15, ha = u >> 4, h = ha / 3, a = ha % 3;
            const int n = n0 + nn;
            const float gv = Msh[h*9+a*3+0]*xyz[n*3+0]
                           + Msh[h*9+a*3+1]*xyz[n*3+1]
                           + Msh[h*9+a*3+2]*xyz[n*3+2];
            kg[(h*3+a)*16 + nn] = K2M * gv;
        }
        __syncthreads();

        // bias fragments (s=1): 8 slots, one per wave (w = 0..7)
        {
            const int  sl  = w;
            const bool isQ = sl < 4;
            const int  h   = sl & 3;
            s16x8 v;
            #pragma unroll
            for (int j = 0; j < 8; j++){
                const int dd = g*8 + j;
                float f;
                if (isQ)
                    f = (dd < 3)  ? kg[(h*3+dd)*16 + col]
                      : (dd == 3) ? rowt[h*16 + col]
                      : (dd == 4) ? 1.0f : 0.0f;
                else
                    f = (dd < 3)  ? xyz[(size_t)(n0+col)*3 + dd]
                      : (dd == 3) ? 1.0f
                      : (dd == 4) ? colt[h*16 + col] : 0.0f;
                v[j] = f2bfs(f);
            }
            ((s16x8*)(ws + (isQ ? QF_OFF : KF_OFF)))[(size_t)(h*128 + bx*2 + 1)*64 + l] = v;
        }
        return;
    }

    // ---- mats 0..2: MFMA GEMM tile + fragment emit ----
    const float* W = (mat == 0) ? Wq : (mat == 1 ? Wk : Wv);
    for (int i = t; i < 4096; i += 512){   // W staging: float4 -> bf16x4
        const float4 w4 = ((const float4*)W)[i];
        const int c = i >> 5, k = (i & 31)*4;
        s16x4 hv;
        hv[0] = f2bfs(w4.x); hv[1] = f2bfs(w4.y);
        hv[2] = f2bfs(w4.z); hv[3] = f2bfs(w4.w);
        *(s16x4*)&wbf[c*136 + k] = hv;     // byte addr c*272+2k: 8B-aligned
    }
    {   // x^T staging: thread t loads one float4, writes 4 transposed bf16
        const int k = t >> 2, part = t & 3;
        const float4 xv = *(const float4*)(x + (size_t)k*1024 + n0 + part*4);
        xbfT[(part*4 + 0)*136 + k] = (ushort)f2bfs(xv.x);
        xbfT[(part*4 + 1)*136 + k] = (ushort)f2bfs(xv.y);
        xbfT[(part*4 + 2)*136 + k] = (ushort)f2bfs(xv.z);
        xbfT[(part*4 + 3)*136 + k] = (ushort)f2bfs(xv.w);
    }
    __syncthreads();

    {   // MFMA: wave w owns m-tile w (c rows w*16..w*16+15), K=128 over 4 slots
        f32x4 acc = {0.f, 0.f, 0.f, 0.f};
        #pragma unroll
        for (int s = 0; s < 4; s++){
            const s16x8 a = *(const s16x8*)&wbf[(w*16 + col)*136 + s*32 + g*8];
            const s16x8 b = *(const s16x8*)&xbfT[col*136 + s*32 + g*8];
            acc = __builtin_amdgcn_mfma_f32_16x16x32_bf16(a, b, acc, 0, 0, 0);
        }
        #pragma unroll
        for (int r = 0; r < 4; r++)
            st[(w*16 + g*4 + r)*17 + col] = acc[r];
    }
    __syncthreads();

    if (w < 4){   // emission by waves 0-3
        const float qs = (mat == 0) ? 0.17677669529663689f : 1.0f;  // 1/sqrt(32)
        if (mat != 2){   // Q/K s=0 fragment: wave = head
            s16x8 v;
            #pragma unroll
            for (int j = 0; j < 8; j++)
                v[j] = f2bfs(st[(w*32 + g*8 + j)*17 + col] * qs);
            ((s16x8*)(ws + (mat == 0 ? QF_OFF : KF_OFF)))[(size_t)(w*128 + bx*2 + 0)*64 + l] = v;
        } else {         // V half-fragments: this block = m-tile bx
            #pragma unroll
            for (int q = 0; q < 2; q++){
                const int tc = w*2 + q;
                s16x4 hv;
                #pragma unroll
                for (int jj = 0; jj < 4; jj++)
                    hv[jj] = f2bfs(st[(tc*16 + col)*17 + g*4 + jj]);
                ((s16x4*)(ws + VF_OFF))[(((size_t)(bx>>1)*8 + tc)*64 + l)*2 + (bx & 1)] = hv;
            }
        }
    }
}

// ---------------- kernel 2: flash attention per (n-tile, head) ----------
// grid (64, 4), block 512 = 8 waves; wave w = m-chunk w. All 8 chunks of one
// (n-tile, head) in one block: softmax combine in LDS (fp32), write final
// normalized AO (bf16 [n][c]). (verbatim R12/R13)
__global__ __launch_bounds__(512) void k_attn(
    const float* __restrict__ ws_c, float* __restrict__ ws)
{
    __shared__ float smx[8*16];    // [w][n16] chunk max
    __shared__ float ssum[8*16];   // [w][n16] chunk sum
    __shared__ float sS[16];       // global denom per n
    __shared__ float so[8*544];    // [w][c32][17] scaled partials (17-pad)

    const int t = threadIdx.x, l = t & 63, w = t >> 6;
    const int bx = blockIdx.x, h = blockIdx.y;
    const int g = l >> 4, col = l & 15;

    const s16x8* QFv = (const s16x8*)(ws_c + QF_OFF);
    const s16x8* KFv = (const s16x8*)(ws_c + KF_OFF);
    const s16x8* VFv = (const s16x8*)(ws_c + VF_OFF);

    const s16x8 bq0 = QFv[(size_t)(h*128 + bx*2 + 0)*64 + l];
    const s16x8 bq1 = QFv[(size_t)(h*128 + bx*2 + 1)*64 + l];

    // scores S^T for this wave's chunk (8 m-tiles, K=64)
    f32x4 sc[8];
    #pragma unroll
    for (int tt = 0; tt < 8; tt++){
        const int mt = w*8 + tt;
        const s16x8 ak0 = KFv[(size_t)(h*128 + mt*2 + 0)*64 + l];
        const s16x8 ak1 = KFv[(size_t)(h*128 + mt*2 + 1)*64 + l];
        f32x4 c = {0.f,0.f,0.f,0.f};
        c = __builtin_amdgcn_mfma_f32_16x16x32_bf16(ak0, bq0, c, 0, 0, 0);
        c = __builtin_amdgcn_mfma_f32_16x16x32_bf16(ak1, bq1, c, 0, 0, 0);
        sc[tt] = c;
    }

    // chunk softmax partials per n (in-lane 32 + lanes l^16, l^32)
    float mx = -3.4e38f;
    #pragma unroll
    for (int tt = 0; tt < 8; tt++)
        #pragma unroll
        for (int r = 0; r < 4; r++) mx = fmaxf(mx, sc[tt][r]);
    mx = fmaxf(mx, __shfl_xor(mx, 16, 64));
    mx = fmaxf(mx, __shfl_xor(mx, 32, 64));

    float sum = 0.f;
    #pragma unroll
    for (int tt = 0; tt < 8; tt++)
        #pragma unroll
        for (int r = 0; r < 4; r++){
            const float e = __builtin_amdgcn_exp2f((sc[tt][r] - mx)*LOG2E);
            sc[tt][r] = e;
            sum += e;
        }
    sum += __shfl_xor(sum, 16, 64);
    sum += __shfl_xor(sum, 32, 64);

    if (l < 16){
        smx[w*16 + col]  = mx;
        ssum[w*16 + col] = sum;
    }

    // pack P as PV B-fragments
    s16x8 pb[4];
    #pragma unroll
    for (int s = 0; s < 4; s++){
        s16x8 b;
        #pragma unroll
        for (int r = 0; r < 4; r++){
            b[r]   = f2bfs(sc[2*s][r]);
            b[4+r] = f2bfs(sc[2*s+1][r]);
        }
        pb[s] = b;
    }

    // PV for this head's channels tc = 2h, 2h+1
    f32x4 o0 = {0.f,0.f,0.f,0.f}, o1 = {0.f,0.f,0.f,0.f};
    #pragma unroll
    for (int s = 0; s < 4; s++){
        const s16x8 av0 = VFv[(size_t)((w*4 + s)*8 + 2*h    )*64 + l];
        const s16x8 av1 = VFv[(size_t)((w*4 + s)*8 + 2*h + 1)*64 + l];
        o0 = __builtin_amdgcn_mfma_f32_16x16x32_bf16(av0, pb[s], o0, 0, 0, 0);
        o1 = __builtin_amdgcn_mfma_f32_16x16x32_bf16(av1, pb[s], o1, 0, 0, 0);
    }
    __syncthreads();   // all smx/ssum visible

    // global max per n; this wave's rescale factor
    float M = -3.4e38f;
    #pragma unroll
    for (int k = 0; k < 8; k++) M = fmaxf(M, smx[k*16 + col]);
    const float lam = __builtin_amdgcn_exp2f((mx - M)*LOG2E);
    if (w == 0 && l < 16){
        float S = 0.f;
        #pragma unroll
        for (int k = 0; k < 8; k++)
            S = fmaf(__builtin_amdgcn_exp2f((smx[k*16 + col] - M)*LOG2E),
                     ssum[k*16 + col], S);
        sS[col] = S;
    }
    // scaled partials to my slot: c_local = (o1?16:0) + g*4 + r, n = col
    #pragma unroll
    for (int r = 0; r < 4; r++){
        so[w*544 + (g*4 + r)*17 + col]        = o0[r]*lam;
        so[w*544 + (16 + g*4 + r)*17 + col]   = o1[r]*lam;
    }
    __syncthreads();

    // final: 512 threads, element (c_local = t&31, n = t>>5)
    {
        const int cl = t & 31, nn = t >> 5;
        float a = 0.f;
        #pragma unroll
        for (int k = 0; k < 8; k++) a += so[k*544 + cl*17 + nn];
        a *= __builtin_amdgcn_rcpf(sS[nn]);
        ((ushort*)(ws + AOT_OFF))[(size_t)(bx*16 + nn)*128 + h*32 + cl] =
            (ushort)f2bfs(a);
    }
}

// ---------------- kernel 3: Wo matmul + residual + LayerNorm -------------
// grid (256), block 512: n-tile of 4, k-loop split across wave-halves.
// Wo staged from the prebuilt bf16 copy. (verbatim R13)
__global__ __launch_bounds__(512) void k_final(
    const float* __restrict__ bo, const float* __restrict__ x,
    const float* __restrict__ gamma, const float* __restrict__ beta,
    const float* __restrict__ ws, float* __restrict__ out)
{
    __shared__ ushort wbf[128*130];   // Wo bf16 [c][k] pitch 130 (33KB)
    __shared__ float alds[128*4];     // [k][nn] then reused as [nn][c]
    __shared__ float redb[2*128*4];   // [kh][c][nn]
    __shared__ float stats[8];        // mu[4], rstd[4]
    const int t  = threadIdx.x;
    const int n0 = blockIdx.x * 4;

    for (int i = t; i < 4096; i += 512){   // stage bf16 Wo: s16x4 loads
        const s16x4 hv = ((const s16x4*)(ws + WOB_OFF))[i];
        const int c = i >> 5, k = (i*4) & 127;
        wbf[c*130 + k + 0] = (ushort)hv[0];
        wbf[c*130 + k + 1] = (ushort)hv[1];
        wbf[c*130 + k + 2] = (ushort)hv[2];
        wbf[c*130 + k + 3] = (ushort)hv[3];
    }
    {   // AO tile: 512 threads, one (c, nn) each (coalesced bf16 read)
        const int c = t & 127, nn = t >> 7;
        alds[c*4 + nn] =
            bf2f(((const ushort*)(ws + AOT_OFF))[(size_t)(n0 + nn)*128 + c]);
    }
    __syncthreads();

    // split-k Wo GEMM: thread (c, q, kh); nn = q*2+{0,1}
    const int c = t & 127, q = (t >> 7) & 1, kh = t >> 8;
    float acc2[2] = {0.f, 0.f};
    const int kbase = kh*64;
    #pragma unroll 4
    for (int kk = 0; kk < 64; kk++){
        const int k = kbase + kk;
        const float  wv = bf2f(wbf[c*130 + k]);
        const float2 a2 = *(const float2*)&alds[k*4 + q*2];
        acc2[0] = fmaf(wv, a2.x, acc2[0]);
        acc2[1] = fmaf(wv, a2.y, acc2[1]);
    }
    redb[(kh*128 + c)*4 + q*2 + 0] = acc2[0];
    redb[(kh*128 + c)*4 + q*2 + 1] = acc2[1];
    __syncthreads();

    // reduce halves + bias + residual (threads 0..255: one (c, q) pair)
    float accv[2];
    if (t < 256){
        const int cc = t & 127, qq = t >> 7;
        const float bov = bo[cc];
        #pragma unroll
        for (int r = 0; r < 2; r++){
            const int nn = qq*2 + r;
            const float v = redb[(0*128 + cc)*4 + nn] + redb[(128 + cc)*4 + nn]
                          + bov + x[(size_t)cc*1024 + n0 + nn];
            accv[r] = v;
            alds[nn*128 + cc] = v;   // lnb [nn][c]
        }
    }
    __syncthreads();

    {   // LN stats: waves 0-3, wave w owns row w
        const int lane = t & 63, w = t >> 6;
        if (w < 4){
            const float v0 = alds[w*128 + lane];
            const float v1 = alds[w*128 + 64 + lane];
            const float s  = wave_sum64(v0 + v1);
            const float qq2 = wave_sum64(fmaf(v0, v0, v1*v1));
            if (lane == 0){
                const float mu  = s * 0.0078125f;
                const float var = qq2 * 0.0078125f - mu*mu;
                stats[w]     = mu;
                stats[4 + w] = rsqrtf(var + 1e-5f);
            }
        }
    }
    __syncthreads();

    if (t < 256){
        const int cc = t & 127, qq = t >> 7;
        const float g = gamma[cc], b = beta[cc];
        const int nn0 = qq*2;
        float2 o2;
        o2.x = (accv[0] - stats[nn0])   * stats[4 + nn0]   * g + b;
        o2.y = (accv[1] - stats[nn0+1]) * stats[4 + nn0+1] * g + b;
        *(float2*)(out + (size_t)cc*1024 + n0 + nn0) = o2;
    }
}

extern "C" void kernel_launch(void* const* d_in, const int* in_sizes, int n_in,
                              void* d_out, int out_size, void* d_ws, size_t ws_size,
                              hipStream_t stream)
{
    const float* x     = (const float*)d_in[0];
    const float* xyz   = (const float*)d_in[1];
    const float* Wq    = (const float*)d_in[2];
    const float* Wk    = (const float*)d_in[3];
    const float* Wv    = (const float*)d_in[4];
    const float* Wp1   = (const float*)d_in[5];
    const float* bp1   = (const float*)d_in[6];
    const float* Wp2   = (const float*)d_in[7];
    const float* bp2   = (const float*)d_in[8];
    const float* Wo    = (const float*)d_in[9];
    const float* bo    = (const float*)d_in[10];
    const float* gamma = (const float*)d_in[11];
    const float* beta  = (const float*)d_in[12];
    float* ws  = (float*)d_ws;
    float* out = (float*)d_out;

    hipLaunchKernelGGL(k_prep,  dim3(64, 4), dim3(512), 0, stream,
                       x, xyz, Wq, Wk, Wv, Wp1, bp1, Wp2, bp2, Wo, ws);
    hipLaunchKernelGGL(k_attn,  dim3(64, 4), dim3(512), 0, stream, ws, ws);
    hipLaunchKernelGGL(k_final, dim3(256),   dim3(512), 0, stream,
                       bo, x, gamma, beta, ws, out);
}